// Round 10
// baseline (99.675 us; speedup 1.0000x reference)
//
#include <hip/hip_runtime.h>
#include <math.h>

#define NB 4
#define NPRED 8400
#define NGT 32
#define NCLS 80
#define ROW 85
#define NSEG 132    // ceil(8400/64); last segment has 16 preds

typedef unsigned long long u64;

// ---------- math helpers (mirror reference fp32 op order) ----------

__device__ __forceinline__ float focal_t(float x, float t) {
    float p = 1.f / (1.f + expf(-x));
    float ce = (fmaxf(x, 0.f) + log1pf(expf(-fabsf(x)))) - x * t; // logaddexp(0,x) - x*t
    float pt = p * t + (1.f - p) * (1.f - t);
    float ompt = 1.f - pt;
    float loss = ce * (ompt * ompt);              // GAMMA=2
    float at = 0.25f * t + 0.75f * (1.f - t);     // ALPHA=0.25
    return at * loss;
}

__device__ __forceinline__ float ciou_f(float x1, float y1, float x2, float y2,
                                        float x1g, float y1g, float x2g, float y2g,
                                        float atan_p, float atan_g) {
    float w1 = x2 - x1, h1 = y2 - y1;
    float wg = x2g - x1g, hg = y2g - y1g;
    float iw = fmaxf(fminf(x2, x2g) - fmaxf(x1, x1g), 0.f);
    float ih = fmaxf(fminf(y2, y2g) - fmaxf(y1, y1g), 0.f);
    float inter = iw * ih;
    float uni = w1 * h1 + wg * hg - inter;
    float iou = inter / (uni + 1e-7f);
    float cw = fmaxf(x2, x2g) - fminf(x1, x1g);
    float ch = fmaxf(y2, y2g) - fminf(y1, y1g);
    float diag = cw * cw + ch * ch + 1e-7f;
    float dx = (x1 + x2 - x1g - x2g) * 0.5f;
    float dy = (y1 + y2 - y1g - y2g) * 0.5f;
    float rho2 = dx * dx + dy * dy;
    float diou = 1.f - iou + rho2 / diag;
    float dd = atan_g - atan_p;
    const float CV = (float)(4.0 / (M_PI * M_PI));
    float v = CV * (dd * dd);
    float alpha = v / (1.f - iou + v + 1e-7f);
    return diou + alpha * v;
}

__device__ __forceinline__ u64 wave_min_u64(u64 k) {
    #pragma unroll
    for (int off = 32; off >= 1; off >>= 1) {
        u64 o = __shfl_xor(k, off);
        k = (o < k) ? o : k;
    }
    return k;
}

// key packs (cost_bits, col). cost >= 0 always -> bit order == value order,
// low word gives the first-index tie-break.
__device__ __forceinline__ u64 pack_key(float v, int idx) {
    return ((u64)__float_as_uint(v) << 32) | (u64)(unsigned)idx;
}

// ---------- K1: wave-per-pred S0/d/box + cost + TOP-2 segment minima ------
// Block = (segment sg of 64 preds, batch b), 512 threads (8 waves).
// No row staging: class logits read coalesced per pred; one barrier total.

__global__ __launch_bounds__(512) void fused_kernel(
        const float* __restrict__ outputs, const float* __restrict__ targets,
        float* __restrict__ s0arr, u64* __restrict__ kt1, u64* __restrict__ kt2,
        double* __restrict__ negbuf, float* __restrict__ gtab,
        int* __restrict__ larr) {
    int sg = blockIdx.x, b = blockIdx.y;
    int tid = threadIdx.x;
    int w = tid >> 6, lane = tid & 63;
    int p0 = sg * 64;
    int nv = (sg == NSEG - 1) ? (NPRED - (NSEG - 1) * 64) : 64;   // 16 or 64

    __shared__ float  dloc[64][33];     // +1 pad: (lane+m)%32 banks, 2-way free
    __shared__ float  boxl[64][5];
    __shared__ float  s_gt[NGT * 5];
    __shared__ int    s_lab[NGT];
    __shared__ double negp[8];

    // GT boxes — same math as reference xywh_to_xyxy + atan
    if (tid < 32) {
        const float* gt = targets + (size_t)(b * NGT + tid) * ROW;
        float xc = gt[0], yc = gt[1], ww = gt[2], hh = gt[3];
        float x1 = xc - ww * 0.5f, y1 = yc - hh * 0.5f;
        float x2 = xc + ww * 0.5f, y2 = yc + hh * 0.5f;
        float at = atanf((x2 - x1) / (y2 - y1));
        s_gt[tid * 5 + 0] = x1; s_gt[tid * 5 + 1] = y1;
        s_gt[tid * 5 + 2] = x2; s_gt[tid * 5 + 3] = y2;
        s_gt[tid * 5 + 4] = at;
        if (sg == 0) {
            float* gp = gtab + (size_t)(b * NGT + tid) * 5;
            gp[0] = x1; gp[1] = y1; gp[2] = x2; gp[3] = y2; gp[4] = at;
        }
    }
    // labels via ballot over the one-hot row (wave w -> 4 GT rows)
    #pragma unroll
    for (int q = 0; q < 4; ++q) {
        int m = w * 4 + q;
        const float* gt = targets + (size_t)(b * NGT + m) * ROW;
        u64 m1 = __ballot(gt[5 + lane] > 0.5f);
        float v2 = (lane < 16) ? gt[69 + lane] : 0.f;
        u64 m2 = __ballot(v2 > 0.5f);
        if (lane == 0) {
            int L = m1 ? (__ffsll(m1) - 1) : (64 + __ffsll(m2) - 1);
            s_lab[m] = L;
            if (sg == 0) larr[b * NGT + m] = L;
        }
    }
    __syncthreads();

    // per-pred phase: wave w handles preds w*8..w*8+7
    double my_neg = 0.0;
    #pragma unroll
    for (int pp = 0; pp < 8; ++pp) {
        int pred = w * 8 + pp;
        bool pv = pred < nv;                 // wave-uniform
        const float* rb = outputs + ((size_t)b * NPRED + p0 + pred) * ROW;
        float xA = 0.f, xB = 0.f, h = 0.f;
        if (pv) {
            xA = rb[5 + lane];               // classes lane, lane+64: coalesced
            if (lane < 16) xB = rb[69 + lane];
            if (lane < 5) h = rb[lane];      // box head + conf
        }
        float fA = focal_t(xA, 0.f);
        float fB = focal_t(xB, 0.f);
        float s = fA;
        if (lane < 16) s += fB;              // same order as proven s0_kernel
        #pragma unroll
        for (int off = 32; off >= 1; off >>= 1) s += __shfl_xor(s, off);

        float xc = __shfl(h, 0), yc = __shfl(h, 1);
        float ww = __shfl(h, 2), hh = __shfl(h, 3), cf = __shfl(h, 4);
        float x1 = xc - ww * 0.5f, y1 = yc - hh * 0.5f;
        float x2 = xc + ww * 0.5f, y2 = yc + hh * 0.5f;
        float atp = atanf((x2 - x1) / (y2 - y1));

        // label terms for m = lane&31 via bpermute (uniform shfl, then select)
        int m = lane & 31;
        int lab = s_lab[m];
        float xlA = __shfl(xA, lab & 63);
        float xlB = __shfl(xB, (lab - 64) & 63);
        float f0A = __shfl(fA, lab & 63);
        float f0B = __shfl(fB, (lab - 64) & 63);
        float xl  = (lab < 64) ? xlA : xlB;
        float f0l = (lab < 64) ? f0A : f0B;
        float f1l = focal_t(xl, 1.f);
        float d = (s - f0l) + f1l;           // (S0 - f0 + f1): reference order

        if (pv) {
            if (lane == 0) {
                boxl[pred][0] = x1; boxl[pred][1] = y1;
                boxl[pred][2] = x2; boxl[pred][3] = y2;
                boxl[pred][4] = atp;
                s0arr[b * NPRED + p0 + pred] = s;
                my_neg += (double)focal_t(cf, 0.f);
            }
            if (lane < 32) dloc[pred][lane] = d;
        }
    }
    if (lane == 0) negp[w] = my_neg;
    __syncthreads();
    if (tid == 0) {
        double t = 0.0;
        #pragma unroll
        for (int k = 0; k < 8; ++k) t += negp[k];
        negbuf[b * NSEG + sg] = t;           // direct write, no atomic
    }

    // cost phase: wave w -> GT rows w*4..w*4+3, lane = pred
    bool valid = lane < nv;
    float bx1 = 0.f, by1 = 0.f, bx2 = 0.f, by2 = 0.f, bat = 0.f;
    if (valid) {
        bx1 = boxl[lane][0]; by1 = boxl[lane][1];
        bx2 = boxl[lane][2]; by2 = boxl[lane][3];
        bat = boxl[lane][4];
    }
    #pragma unroll
    for (int q = 0; q < 4; ++q) {
        int m = w * 4 + q;
        const float* gp = s_gt + m * 5;
        float cost = INFINITY;
        if (valid) {
            float cc = ciou_f(bx1, by1, bx2, by2, gp[0], gp[1], gp[2], gp[3],
                              bat, gp[4]);
            cost = cc + dloc[lane][m] / 80.f;
        }
        u64 k = pack_key(cost, valid ? (p0 + lane) : NPRED);
        u64 k1 = wave_min_u64(k);
        int i1 = (int)(unsigned)(k1 & 0xffffffffull);
        u64 kx = ((p0 + lane) == i1) ? ~0ull : k;   // exclude winner lane
        u64 k2 = wave_min_u64(kx);
        if (lane == 0) {
            kt1[(size_t)(b * NGT + m) * NSEG + sg] = k1;
            kt2[(size_t)(b * NGT + m) * NSEG + sg] = k2;
        }
    }
}

// ---------- K2: ONE block, 1024 threads (16 waves) -----------------------
// Phase 1: coalesced rowmin over kt1. Phase 2a: waves 0-3 serial assignment
// (reference semantics, R9 bitmask logic; repair via top-2 fallback, exact).
// Phase 2b: waves 4-7 neg sums. Phase 3: finalize; wave-0 combine.

__global__ __launch_bounds__(1024) void assign_finalize_kernel(
        const float* __restrict__ outputs, const float* __restrict__ targets,
        const float* __restrict__ s0arr, const u64* __restrict__ kt1,
        const u64* __restrict__ kt2, const double* __restrict__ negbuf,
        const float* __restrict__ gtab, const int* __restrict__ larr,
        float* __restrict__ out) {
    int tid = threadIdx.x;
    int w = tid >> 6, lane = tid & 63;

    __shared__ u64    taken[NB][NSEG], poison[NB][NSEG];
    __shared__ float  s_gt[NB * NGT * 5];
    __shared__ int    s_lab[NB * NGT];
    __shared__ int    rmi[NB][NGT];
    __shared__ int    s_midx[NB][NGT];
    __shared__ float  s_siou[NB * NGT], s_cls[NB * NGT], s_adj[NB * NGT];
    __shared__ double s_ns[NB];

    for (int k = tid; k < NB * NSEG; k += 1024) {
        ((u64*)taken)[k] = 0ull; ((u64*)poison)[k] = 0ull;
    }
    if (tid < NB * NGT * 5) s_gt[tid] = gtab[tid];
    if (tid < NB * NGT) s_lab[tid] = larr[tid];

    // Phase 1: rowmin, wave w -> rows w*8..w*8+7 (row = b*32+r), coalesced
    #pragma unroll
    for (int q = 0; q < 8; ++q) {
        int row = w * 8 + q;
        const u64* kr = kt1 + (size_t)row * NSEG;
        u64 k = kr[lane];
        { u64 v = kr[lane + 64]; if (v < k) k = v; }
        if (lane < NSEG - 128) { u64 v = kr[lane + 128]; if (v < k) k = v; }
        k = wave_min_u64(k);
        if (lane == 0) rmi[row >> 5][row & 31] = (int)(unsigned)(k & 0xffffffffull);
    }
    __syncthreads();

    // Phase 2a: waves 0-3 run the serial assignment for batch b=w
    if (w < NB) {
        int b = w;
        const float* Ob = outputs + (size_t)b * NPRED * ROW;
        const float* S0b = s0arr + (size_t)b * NPRED;
        for (int i = 0; i < NGT; ++i) {
            int j1 = rmi[b][i];
            if ((poison[b][j1 >> 6] >> (j1 & 63)) & 1ull) {
                // repair: effective per-seg key = k1 if argmin alive, else k2
                // if alive, else recompute (both-top2-poisoned: ~never).
                const u64* k1r = kt1 + ((size_t)b * NGT + i) * NSEG;
                const u64* k2r = kt2 + ((size_t)b * NGT + i) * NSEG;
                const float* gp = &s_gt[(b * NGT + i) * 5];
                int lab = s_lab[b * NGT + i];
                u64 best = ~0ull;
                for (int k0 = 0; k0 < NSEG; k0 += 64) {
                    int s = k0 + lane;
                    u64 eff = ~0ull; bool rc = false;
                    if (s < NSEG) {
                        u64 ka = k1r[s];
                        int ia = (int)(unsigned)(ka & 0xffffffffull);
                        if (!((poison[b][ia >> 6] >> (ia & 63)) & 1ull)) eff = ka;
                        else {
                            u64 kb = k2r[s];
                            int ib = (int)(unsigned)(kb & 0xffffffffull);
                            if (ib < NPRED && !((poison[b][ib >> 6] >> (ib & 63)) & 1ull)) eff = kb;
                            else rc = true;
                        }
                    }
                    u64 rm = __ballot(rc);
                    while (rm) {
                        int sgg = k0 + (__ffsll(rm) - 1);
                        rm &= rm - 1;
                        int col = (sgg << 6) + lane;
                        bool cv = (col < NPRED) && !((poison[b][col >> 6] >> (col & 63)) & 1ull);
                        float vv = INFINITY;
                        if (cv) {
                            const float* pr = Ob + (size_t)col * ROW;
                            float xc = pr[0], yc = pr[1], ww2 = pr[2], hh2 = pr[3];
                            float x1 = xc - ww2 * 0.5f, y1 = yc - hh2 * 0.5f;
                            float x2 = xc + ww2 * 0.5f, y2 = yc + hh2 * 0.5f;
                            float atan_p = atanf((x2 - x1) / (y2 - y1));
                            float cc = ciou_f(x1, y1, x2, y2, gp[0], gp[1], gp[2], gp[3],
                                              atan_p, gp[4]);
                            float xl = pr[5 + lab];
                            vv = cc + (S0b[col] - focal_t(xl, 0.f) + focal_t(xl, 1.f)) / 80.f;
                        }
                        u64 key = pack_key(vv, cv ? col : NPRED);
                        key = wave_min_u64(key);
                        if (s == sgg) eff = key;
                    }
                    if (eff < best) best = eff;
                }
                best = wave_min_u64(best);
                j1 = (int)(unsigned)(best & 0xffffffffull);
            }
            bool tk = (taken[b][j1 >> 6] >> (j1 & 63)) & 1ull;
            if (!tk) {
                if (lane == 0) { taken[b][j1 >> 6] |= 1ull << (j1 & 63); s_midx[b][i] = j1; }
            } else {
                // collision: first free col is in word 0 (<=32 taken bits ever)
                u64 tw = taken[b][0];
                int bit = __ffsll(~tw) - 1;
                u64 add = (lane == 0) ? (tw & ((bit == 0) ? 0ull : ((1ull << bit) - 1ull))) : 0ull;
                if ((j1 >> 6) == lane) add |= 1ull << (j1 & 63);
                if (add) poison[b][lane] |= add;
                int u2 = lane + 64;
                if ((j1 >> 6) == u2) poison[b][u2] |= 1ull << (j1 & 63);
                int u3 = lane + 128;
                if (u3 < NSEG && (j1 >> 6) == u3) poison[b][u3] |= 1ull << (j1 & 63);
                if (lane == 0) { taken[b][0] |= 1ull << bit; s_midx[b][i] = bit; }
            }
        }
    } else if (w < 2 * NB) {
        // Phase 2b: waves 4-7 sum neg partials for batch b=w-4 (concurrent)
        int b = w - NB;
        double ng = negbuf[b * NSEG + lane] + negbuf[b * NSEG + 64 + lane]
                  + ((lane < NSEG - 128) ? negbuf[b * NSEG + 128 + lane] : 0.0);
        #pragma unroll
        for (int off = 32; off >= 1; off >>= 1) ng += __shfl_xor(ng, off);
        if (lane == 0) s_ns[b] = ng;
    }
    __syncthreads();

    // Phase 3: finalize partials
    if (tid < NB * NGT) {          // 128 threads: ciou + obj-adjust per pair
        int b = tid >> 5, m = tid & 31;
        int j = s_midx[b][m];
        const float* pr = outputs + ((size_t)b * NPRED + j) * ROW;
        float xc = pr[0], yc = pr[1], ww = pr[2], hh = pr[3];
        float x1 = xc - ww * 0.5f, y1 = yc - hh * 0.5f;
        float x2 = xc + ww * 0.5f, y2 = yc + hh * 0.5f;
        float atan_p = atanf((x2 - x1) / (y2 - y1));
        const float* gp = &s_gt[tid * 5];
        s_siou[tid] = ciou_f(x1, y1, x2, y2, gp[0], gp[1], gp[2], gp[3], atan_p, gp[4]);
        float conf = pr[4];
        s_adj[tid] = focal_t(conf, 1.f) - focal_t(conf, 0.f);
    }
    // cls: wave w -> pairs w*8..w*8+7, lane-parallel over classes
    #pragma unroll
    for (int q = 0; q < 8; ++q) {
        int p = w * 8 + q;
        int b = p >> 5, m = p & 31;
        int j = s_midx[b][m];
        const float* pr = outputs + ((size_t)b * NPRED + j) * ROW;
        const float* gt = targets + ((size_t)b * NGT + m) * ROW;
        float s = focal_t(pr[5 + lane], gt[5 + lane]);
        if (lane < 16) s += focal_t(pr[69 + lane], gt[69 + lane]);
        #pragma unroll
        for (int off = 32; off >= 1; off >>= 1) s += __shfl_xor(s, off);
        if (lane == 0) s_cls[p] = s / 80.f;
    }
    __syncthreads();

    // wave 0: fixed-order combine, write out
    if (w == 0) {
        double ss = (double)s_siou[lane] + (double)s_siou[lane + 64];
        double cs = (double)s_cls[lane] + (double)s_cls[lane + 64];
        double as = (double)s_adj[lane] + (double)s_adj[lane + 64];
        double ns = (lane < NB) ? s_ns[lane] : 0.0;
        #pragma unroll
        for (int off = 32; off >= 1; off >>= 1) {
            ss += __shfl_xor(ss, off);
            cs += __shfl_xor(cs, off);
            as += __shfl_xor(as, off);
            ns += __shfl_xor(ns, off);
        }
        if (lane == 0) {
            float siou = (float)(ss / 128.0);
            float cls  = (float)(cs / 128.0);
            float obj  = (float)((ns + as) / (double)(NB * NPRED));
            out[0] = 2.0f * siou + 2.0f * obj + 2.0f * cls;
            out[1] = siou;
            out[2] = obj;
            out[3] = cls;
        }
    }
}

// ---------- launch ----------

extern "C" void kernel_launch(void* const* d_in, const int* in_sizes, int n_in,
                              void* d_out, int out_size, void* d_ws, size_t ws_size,
                              hipStream_t stream) {
    const float* outputs = (const float*)d_in[0];
    const float* targets = (const float*)d_in[1];
    float* out = (float*)d_out;

    char* ws = (char*)d_ws;
    double* negbuf = (double*)ws;                     // 4*132*8 = 4224 B
    float* gtab = (float*)(ws + 4352);                // 2560 B
    int* larr = (int*)(ws + 7040);                    // 512 B
    float* s0arr = (float*)(ws + 7552);               // 134400 B
    u64* kt1 = (u64*)(ws + 141952);                   // 135168 B
    u64* kt2 = (u64*)(ws + 277120);                   // 135168 B

    dim3 g1(NSEG, NB);                                // 132 x 4 segment blocks
    fused_kernel<<<g1, 512, 0, stream>>>(outputs, targets, s0arr, kt1, kt2,
                                         negbuf, gtab, larr);

    assign_finalize_kernel<<<1, 1024, 0, stream>>>(outputs, targets, s0arr,
                                                   kt1, kt2, negbuf, gtab,
                                                   larr, out);
}

// Round 11
// 72.031 us; speedup vs baseline: 1.3838x; 1.3838x over previous
//
#include <hip/hip_runtime.h>
#include <math.h>

#define NB 4
#define NPRED 8400
#define NGT 32
#define NCLS 80
#define ROW 85
#define NSEG 132    // ceil(8400/64); last segment has 16 preds

typedef unsigned long long u64;

// ---------- math helpers (mirror reference fp32 op order) ----------

__device__ __forceinline__ float focal_t(float x, float t) {
    float p = 1.f / (1.f + expf(-x));
    float ce = (fmaxf(x, 0.f) + log1pf(expf(-fabsf(x)))) - x * t; // logaddexp(0,x) - x*t
    float pt = p * t + (1.f - p) * (1.f - t);
    float ompt = 1.f - pt;
    float loss = ce * (ompt * ompt);              // GAMMA=2
    float at = 0.25f * t + 0.75f * (1.f - t);     // ALPHA=0.25
    return at * loss;
}

__device__ __forceinline__ float ciou_f(float x1, float y1, float x2, float y2,
                                        float x1g, float y1g, float x2g, float y2g,
                                        float atan_p, float atan_g) {
    float w1 = x2 - x1, h1 = y2 - y1;
    float wg = x2g - x1g, hg = y2g - y1g;
    float iw = fmaxf(fminf(x2, x2g) - fmaxf(x1, x1g), 0.f);
    float ih = fmaxf(fminf(y2, y2g) - fmaxf(y1, y1g), 0.f);
    float inter = iw * ih;
    float uni = w1 * h1 + wg * hg - inter;
    float iou = inter / (uni + 1e-7f);
    float cw = fmaxf(x2, x2g) - fminf(x1, x1g);
    float ch = fmaxf(y2, y2g) - fminf(y1, y1g);
    float diag = cw * cw + ch * ch + 1e-7f;
    float dx = (x1 + x2 - x1g - x2g) * 0.5f;
    float dy = (y1 + y2 - y1g - y2g) * 0.5f;
    float rho2 = dx * dx + dy * dy;
    float diou = 1.f - iou + rho2 / diag;
    float dd = atan_g - atan_p;
    const float CV = (float)(4.0 / (M_PI * M_PI));
    float v = CV * (dd * dd);
    float alpha = v / (1.f - iou + v + 1e-7f);
    return diou + alpha * v;
}

__device__ __forceinline__ u64 wave_min_u64(u64 k) {
    #pragma unroll
    for (int off = 32; off >= 1; off >>= 1) {
        u64 o = __shfl_xor(k, off);
        k = (o < k) ? o : k;
    }
    return k;
}

// key packs (cost_bits, col). cost >= 0 always -> bit order == value order,
// low word gives the first-index tie-break.
__device__ __forceinline__ u64 pack_key(float v, int idx) {
    return ((u64)__float_as_uint(v) << 32) | (u64)(unsigned)idx;
}

// ---------- K1: fused staging + S0 + cost + TOP-2 segment minima ----------
// Block = (segment sg, batch b), 512 threads (8 waves). R9 structure:
// LDS row staging (conflict-free stride 85), chunked S0, cost phase reads
// rows/LDS. Deltas vs R9: 512 threads (2x waves for latency hiding) and
// top-2 keys per segment (cheap K2 repair).

__global__ __launch_bounds__(512) void fused_kernel(
        const float* __restrict__ outputs, const float* __restrict__ targets,
        float* __restrict__ s0arr, u64* __restrict__ kt1, u64* __restrict__ kt2,
        double* __restrict__ negbuf, float* __restrict__ gtab,
        int* __restrict__ larr) {
    int sg = blockIdx.x, b = blockIdx.y;
    int tid = threadIdx.x;
    int w = tid >> 6, lane = tid & 63;
    int p0 = sg * 64;
    int nv = (sg == NSEG - 1) ? (NPRED - (NSEG - 1) * 64) : 64;   // 16 or 64

    __shared__ float rows[64 * ROW];        // stride 85 floats -> conflict-free
    __shared__ float s_part[8 * 64];
    __shared__ float s_s0[64];
    __shared__ float s_gt[NGT * 5];
    __shared__ int   s_lab[NGT];

    // stage pred rows coalesced (contiguous, 16B-aligned)
    const float4* src4 = (const float4*)(outputs + ((size_t)b * NPRED + p0) * ROW);
    float4* dst4 = (float4*)rows;
    int cnt4 = nv * ROW / 4;                // 1360 or 340, exact
    for (int k = tid; k < cnt4; k += 512) dst4[k] = src4[k];

    // GT boxes (parallel) — same math as reference xywh_to_xyxy + atan
    if (tid < 32) {
        const float* gt = targets + (size_t)(b * NGT + tid) * ROW;
        float xc = gt[0], yc = gt[1], ww = gt[2], hh = gt[3];
        float x1 = xc - ww * 0.5f, y1 = yc - hh * 0.5f;
        float x2 = xc + ww * 0.5f, y2 = yc + hh * 0.5f;
        float at = atanf((x2 - x1) / (y2 - y1));
        s_gt[tid * 5 + 0] = x1; s_gt[tid * 5 + 1] = y1;
        s_gt[tid * 5 + 2] = x2; s_gt[tid * 5 + 3] = y2;
        s_gt[tid * 5 + 4] = at;
        if (sg == 0) {
            float* gp = gtab + (size_t)(b * NGT + tid) * 5;
            gp[0] = x1; gp[1] = y1; gp[2] = x2; gp[3] = y2; gp[4] = at;
        }
    }
    // labels via ballot over the one-hot row (wave w -> 4 GT rows)
    #pragma unroll
    for (int q = 0; q < 4; ++q) {
        int m = w * 4 + q;
        const float* gt = targets + (size_t)(b * NGT + m) * ROW;
        u64 m1 = __ballot(gt[5 + lane] > 0.5f);
        float v2 = (lane < 16) ? gt[69 + lane] : 0.f;
        u64 m2 = __ballot(v2 > 0.5f);
        if (lane == 0) {
            int L = m1 ? (__ffsll(m1) - 1) : (64 + __ffsll(m2) - 1);
            s_lab[m] = L;
            if (sg == 0) larr[b * NGT + m] = L;
        }
    }
    __syncthreads();

    // S0: pred = lane, chunk w covers 10 classes
    {
        float s = 0.f;
        if (lane < nv) {
            const float* r = rows + lane * ROW;
            int c0 = w * 10;
            #pragma unroll
            for (int c = 0; c < 10; ++c) s += focal_t(r[5 + c0 + c], 0.f);
        }
        s_part[w * 64 + lane] = s;
    }
    __syncthreads();
    if (tid < 64) {
        float s = s_part[tid];
        #pragma unroll
        for (int c = 1; c < 8; ++c) s += s_part[c * 64 + tid];
        s_s0[tid] = s;
        if (tid < nv) s0arr[b * NPRED + p0 + tid] = s;
        double ng = (tid < nv) ? (double)focal_t(rows[tid * ROW + 4], 0.f) : 0.0;
        #pragma unroll
        for (int off = 32; off >= 1; off >>= 1) ng += __shfl_xor(ng, off);
        if (tid == 0) negbuf[b * NSEG + sg] = ng;   // direct write, no atomic
    }
    __syncthreads();

    // cost + top-2 packed segment minima: wave w -> GT rows w*4..w*4+3
    bool valid = lane < nv;
    const float* r = rows + lane * ROW;
    float x1 = 0.f, y1 = 0.f, x2 = 0.f, y2 = 0.f, atan_p = 0.f, S0 = 0.f;
    if (valid) {
        float xc = r[0], yc = r[1], ww = r[2], hh = r[3];
        x1 = xc - ww * 0.5f; y1 = yc - hh * 0.5f;
        x2 = xc + ww * 0.5f; y2 = yc + hh * 0.5f;
        atan_p = atanf((x2 - x1) / (y2 - y1));
        S0 = s_s0[lane];
    }
    #pragma unroll
    for (int q = 0; q < 4; ++q) {
        int m = w * 4 + q;
        const float* gp = s_gt + m * 5;
        float cost = INFINITY;
        if (valid) {
            float cc = ciou_f(x1, y1, x2, y2, gp[0], gp[1], gp[2], gp[3],
                              atan_p, gp[4]);
            float xl = r[5 + s_lab[m]];
            cost = cc + (S0 - focal_t(xl, 0.f) + focal_t(xl, 1.f)) / 80.f;
        }
        u64 k = pack_key(cost, valid ? (p0 + lane) : NPRED);
        u64 k1 = wave_min_u64(k);
        int i1 = (int)(unsigned)(k1 & 0xffffffffull);
        u64 kx = ((p0 + lane) == i1) ? ~0ull : k;   // exclude winner lane
        u64 k2 = wave_min_u64(kx);
        if (lane == 0) {
            kt1[(size_t)(b * NGT + m) * NSEG + sg] = k1;
            kt2[(size_t)(b * NGT + m) * NSEG + sg] = k2;
        }
    }
}

// ---------- K2: ONE block, 1024 threads (16 waves) — R10 version verbatim --
// Phase 1: coalesced rowmin over kt1. Phase 2a: waves 0-3 serial assignment
// (reference semantics; repair via top-2 fallback, exact). Phase 2b: waves
// 4-7 neg sums. Phase 3: finalize; wave-0 combine.

__global__ __launch_bounds__(1024) void assign_finalize_kernel(
        const float* __restrict__ outputs, const float* __restrict__ targets,
        const float* __restrict__ s0arr, const u64* __restrict__ kt1,
        const u64* __restrict__ kt2, const double* __restrict__ negbuf,
        const float* __restrict__ gtab, const int* __restrict__ larr,
        float* __restrict__ out) {
    int tid = threadIdx.x;
    int w = tid >> 6, lane = tid & 63;

    __shared__ u64    taken[NB][NSEG], poison[NB][NSEG];
    __shared__ float  s_gt[NB * NGT * 5];
    __shared__ int    s_lab[NB * NGT];
    __shared__ int    rmi[NB][NGT];
    __shared__ int    s_midx[NB][NGT];
    __shared__ float  s_siou[NB * NGT], s_cls[NB * NGT], s_adj[NB * NGT];
    __shared__ double s_ns[NB];

    for (int k = tid; k < NB * NSEG; k += 1024) {
        ((u64*)taken)[k] = 0ull; ((u64*)poison)[k] = 0ull;
    }
    if (tid < NB * NGT * 5) s_gt[tid] = gtab[tid];
    if (tid < NB * NGT) s_lab[tid] = larr[tid];

    // Phase 1: rowmin, wave w -> rows w*8..w*8+7 (row = b*32+r), coalesced
    #pragma unroll
    for (int q = 0; q < 8; ++q) {
        int row = w * 8 + q;
        const u64* kr = kt1 + (size_t)row * NSEG;
        u64 k = kr[lane];
        { u64 v = kr[lane + 64]; if (v < k) k = v; }
        if (lane < NSEG - 128) { u64 v = kr[lane + 128]; if (v < k) k = v; }
        k = wave_min_u64(k);
        if (lane == 0) rmi[row >> 5][row & 31] = (int)(unsigned)(k & 0xffffffffull);
    }
    __syncthreads();

    // Phase 2a: waves 0-3 run the serial assignment for batch b=w
    if (w < NB) {
        int b = w;
        const float* Ob = outputs + (size_t)b * NPRED * ROW;
        const float* S0b = s0arr + (size_t)b * NPRED;
        for (int i = 0; i < NGT; ++i) {
            int j1 = rmi[b][i];
            if ((poison[b][j1 >> 6] >> (j1 & 63)) & 1ull) {
                // repair: effective per-seg key = k1 if argmin alive, else k2
                // if alive, else recompute (both-top2-poisoned: ~never).
                const u64* k1r = kt1 + ((size_t)b * NGT + i) * NSEG;
                const u64* k2r = kt2 + ((size_t)b * NGT + i) * NSEG;
                const float* gp = &s_gt[(b * NGT + i) * 5];
                int lab = s_lab[b * NGT + i];
                u64 best = ~0ull;
                for (int k0 = 0; k0 < NSEG; k0 += 64) {
                    int s = k0 + lane;
                    u64 eff = ~0ull; bool rc = false;
                    if (s < NSEG) {
                        u64 ka = k1r[s];
                        int ia = (int)(unsigned)(ka & 0xffffffffull);
                        if (!((poison[b][ia >> 6] >> (ia & 63)) & 1ull)) eff = ka;
                        else {
                            u64 kb = k2r[s];
                            int ib = (int)(unsigned)(kb & 0xffffffffull);
                            if (ib < NPRED && !((poison[b][ib >> 6] >> (ib & 63)) & 1ull)) eff = kb;
                            else rc = true;
                        }
                    }
                    u64 rm = __ballot(rc);
                    while (rm) {
                        int sgg = k0 + (__ffsll(rm) - 1);
                        rm &= rm - 1;
                        int col = (sgg << 6) + lane;
                        bool cv = (col < NPRED) && !((poison[b][col >> 6] >> (col & 63)) & 1ull);
                        float vv = INFINITY;
                        if (cv) {
                            const float* pr = Ob + (size_t)col * ROW;
                            float xc = pr[0], yc = pr[1], ww2 = pr[2], hh2 = pr[3];
                            float x1 = xc - ww2 * 0.5f, y1 = yc - hh2 * 0.5f;
                            float x2 = xc + ww2 * 0.5f, y2 = yc + hh2 * 0.5f;
                            float atan_p = atanf((x2 - x1) / (y2 - y1));
                            float cc = ciou_f(x1, y1, x2, y2, gp[0], gp[1], gp[2], gp[3],
                                              atan_p, gp[4]);
                            float xl = pr[5 + lab];
                            vv = cc + (S0b[col] - focal_t(xl, 0.f) + focal_t(xl, 1.f)) / 80.f;
                        }
                        u64 key = pack_key(vv, cv ? col : NPRED);
                        key = wave_min_u64(key);
                        if (s == sgg) eff = key;
                    }
                    if (eff < best) best = eff;
                }
                best = wave_min_u64(best);
                j1 = (int)(unsigned)(best & 0xffffffffull);
            }
            bool tk = (taken[b][j1 >> 6] >> (j1 & 63)) & 1ull;
            if (!tk) {
                if (lane == 0) { taken[b][j1 >> 6] |= 1ull << (j1 & 63); s_midx[b][i] = j1; }
            } else {
                // collision: first free col is in word 0 (<=32 taken bits ever)
                u64 tw = taken[b][0];
                int bit = __ffsll(~tw) - 1;
                u64 add = (lane == 0) ? (tw & ((bit == 0) ? 0ull : ((1ull << bit) - 1ull))) : 0ull;
                if ((j1 >> 6) == lane) add |= 1ull << (j1 & 63);
                if (add) poison[b][lane] |= add;
                int u2 = lane + 64;
                if ((j1 >> 6) == u2) poison[b][u2] |= 1ull << (j1 & 63);
                int u3 = lane + 128;
                if (u3 < NSEG && (j1 >> 6) == u3) poison[b][u3] |= 1ull << (j1 & 63);
                if (lane == 0) { taken[b][0] |= 1ull << bit; s_midx[b][i] = bit; }
            }
        }
    } else if (w < 2 * NB) {
        // Phase 2b: waves 4-7 sum neg partials for batch b=w-4 (concurrent)
        int b = w - NB;
        double ng = negbuf[b * NSEG + lane] + negbuf[b * NSEG + 64 + lane]
                  + ((lane < NSEG - 128) ? negbuf[b * NSEG + 128 + lane] : 0.0);
        #pragma unroll
        for (int off = 32; off >= 1; off >>= 1) ng += __shfl_xor(ng, off);
        if (lane == 0) s_ns[b] = ng;
    }
    __syncthreads();

    // Phase 3: finalize partials
    if (tid < NB * NGT) {          // 128 threads: ciou + obj-adjust per pair
        int b = tid >> 5, m = tid & 31;
        int j = s_midx[b][m];
        const float* pr = outputs + ((size_t)b * NPRED + j) * ROW;
        float xc = pr[0], yc = pr[1], ww = pr[2], hh = pr[3];
        float x1 = xc - ww * 0.5f, y1 = yc - hh * 0.5f;
        float x2 = xc + ww * 0.5f, y2 = yc + hh * 0.5f;
        float atan_p = atanf((x2 - x1) / (y2 - y1));
        const float* gp = &s_gt[tid * 5];
        s_siou[tid] = ciou_f(x1, y1, x2, y2, gp[0], gp[1], gp[2], gp[3], atan_p, gp[4]);
        float conf = pr[4];
        s_adj[tid] = focal_t(conf, 1.f) - focal_t(conf, 0.f);
    }
    // cls: wave w -> pairs w*8..w*8+7, lane-parallel over classes
    #pragma unroll
    for (int q = 0; q < 8; ++q) {
        int p = w * 8 + q;
        int b = p >> 5, m = p & 31;
        int j = s_midx[b][m];
        const float* pr = outputs + ((size_t)b * NPRED + j) * ROW;
        const float* gt = targets + ((size_t)b * NGT + m) * ROW;
        float s = focal_t(pr[5 + lane], gt[5 + lane]);
        if (lane < 16) s += focal_t(pr[69 + lane], gt[69 + lane]);
        #pragma unroll
        for (int off = 32; off >= 1; off >>= 1) s += __shfl_xor(s, off);
        if (lane == 0) s_cls[p] = s / 80.f;
    }
    __syncthreads();

    // wave 0: fixed-order combine, write out
    if (w == 0) {
        double ss = (double)s_siou[lane] + (double)s_siou[lane + 64];
        double cs = (double)s_cls[lane] + (double)s_cls[lane + 64];
        double as = (double)s_adj[lane] + (double)s_adj[lane + 64];
        double ns = (lane < NB) ? s_ns[lane] : 0.0;
        #pragma unroll
        for (int off = 32; off >= 1; off >>= 1) {
            ss += __shfl_xor(ss, off);
            cs += __shfl_xor(cs, off);
            as += __shfl_xor(as, off);
            ns += __shfl_xor(ns, off);
        }
        if (lane == 0) {
            float siou = (float)(ss / 128.0);
            float cls  = (float)(cs / 128.0);
            float obj  = (float)((ns + as) / (double)(NB * NPRED));
            out[0] = 2.0f * siou + 2.0f * obj + 2.0f * cls;
            out[1] = siou;
            out[2] = obj;
            out[3] = cls;
        }
    }
}

// ---------- launch ----------

extern "C" void kernel_launch(void* const* d_in, const int* in_sizes, int n_in,
                              void* d_out, int out_size, void* d_ws, size_t ws_size,
                              hipStream_t stream) {
    const float* outputs = (const float*)d_in[0];
    const float* targets = (const float*)d_in[1];
    float* out = (float*)d_out;

    char* ws = (char*)d_ws;
    double* negbuf = (double*)ws;                     // 4*132*8 = 4224 B
    float* gtab = (float*)(ws + 4352);                // 2560 B
    int* larr = (int*)(ws + 7040);                    // 512 B
    float* s0arr = (float*)(ws + 7552);               // 134400 B
    u64* kt1 = (u64*)(ws + 141952);                   // 135168 B
    u64* kt2 = (u64*)(ws + 277120);                   // 135168 B

    dim3 g1(NSEG, NB);                                // 132 x 4 segment blocks
    fused_kernel<<<g1, 512, 0, stream>>>(outputs, targets, s0arr, kt1, kt2,
                                         negbuf, gtab, larr);

    assign_finalize_kernel<<<1, 1024, 0, stream>>>(outputs, targets, s0arr,
                                                   kt1, kt2, negbuf, gtab,
                                                   larr, out);
}

// Round 12
// 53.407 us; speedup vs baseline: 1.8663x; 1.3487x over previous
//
#include <hip/hip_runtime.h>
#include <math.h>

#define NB 4
#define NPRED 8400
#define NGT 32
#define NCLS 80
#define ROW 85
#define NSEG 132    // ceil(8400/64); last segment has 16 preds

typedef unsigned long long u64;

// ---------- math helpers (mirror reference fp32 op order) ----------

__device__ __forceinline__ float focal_t(float x, float t) {
    float p = 1.f / (1.f + expf(-x));
    float ce = (fmaxf(x, 0.f) + log1pf(expf(-fabsf(x)))) - x * t; // logaddexp(0,x) - x*t
    float pt = p * t + (1.f - p) * (1.f - t);
    float ompt = 1.f - pt;
    float loss = ce * (ompt * ompt);              // GAMMA=2
    float at = 0.25f * t + 0.75f * (1.f - t);     // ALPHA=0.25
    return at * loss;
}

__device__ __forceinline__ float ciou_f(float x1, float y1, float x2, float y2,
                                        float x1g, float y1g, float x2g, float y2g,
                                        float atan_p, float atan_g) {
    float w1 = x2 - x1, h1 = y2 - y1;
    float wg = x2g - x1g, hg = y2g - y1g;
    float iw = fmaxf(fminf(x2, x2g) - fmaxf(x1, x1g), 0.f);
    float ih = fmaxf(fminf(y2, y2g) - fmaxf(y1, y1g), 0.f);
    float inter = iw * ih;
    float uni = w1 * h1 + wg * hg - inter;
    float iou = inter / (uni + 1e-7f);
    float cw = fmaxf(x2, x2g) - fminf(x1, x1g);
    float ch = fmaxf(y2, y2g) - fminf(y1, y1g);
    float diag = cw * cw + ch * ch + 1e-7f;
    float dx = (x1 + x2 - x1g - x2g) * 0.5f;
    float dy = (y1 + y2 - y1g - y2g) * 0.5f;
    float rho2 = dx * dx + dy * dy;
    float diou = 1.f - iou + rho2 / diag;
    float dd = atan_g - atan_p;
    const float CV = (float)(4.0 / (M_PI * M_PI));
    float v = CV * (dd * dd);
    float alpha = v / (1.f - iou + v + 1e-7f);
    return diou + alpha * v;
}

__device__ __forceinline__ u64 wave_min_u64(u64 k) {
    #pragma unroll
    for (int off = 32; off >= 1; off >>= 1) {
        u64 o = __shfl_xor(k, off);
        k = (o < k) ? o : k;
    }
    return k;
}

// key packs (cost_bits, col). cost >= 0 always -> bit order == value order,
// low word gives the first-index tie-break.
__device__ __forceinline__ u64 pack_key(float v, int idx) {
    return ((u64)__float_as_uint(v) << 32) | (u64)(unsigned)idx;
}

// ---------- K1: fused staging + S0 + cost + TOP-2 segment minima ----------
// Block = (segment sg, batch b), 512 threads. R11 structure; delta: top-2
// argmin via f32 butterfly + ballot (lane order == pred order within a
// segment, so lowest set bit == lowest index; exact, incl. ties).

__global__ __launch_bounds__(512) void fused_kernel(
        const float* __restrict__ outputs, const float* __restrict__ targets,
        float* __restrict__ s0arr, u64* __restrict__ kt1, u64* __restrict__ kt2,
        double* __restrict__ negbuf, float* __restrict__ gtab,
        int* __restrict__ larr) {
    int sg = blockIdx.x, b = blockIdx.y;
    int tid = threadIdx.x;
    int w = tid >> 6, lane = tid & 63;
    int p0 = sg * 64;
    int nv = (sg == NSEG - 1) ? (NPRED - (NSEG - 1) * 64) : 64;   // 16 or 64

    __shared__ float rows[64 * ROW];        // stride 85 floats -> conflict-free
    __shared__ float s_part[8 * 64];
    __shared__ float s_s0[64];
    __shared__ float s_gt[NGT * 5];
    __shared__ int   s_lab[NGT];

    // stage pred rows coalesced (contiguous, 16B-aligned)
    const float4* src4 = (const float4*)(outputs + ((size_t)b * NPRED + p0) * ROW);
    float4* dst4 = (float4*)rows;
    int cnt4 = nv * ROW / 4;                // 1360 or 340, exact
    for (int k = tid; k < cnt4; k += 512) dst4[k] = src4[k];

    // GT boxes (parallel) — same math as reference xywh_to_xyxy + atan
    if (tid < 32) {
        const float* gt = targets + (size_t)(b * NGT + tid) * ROW;
        float xc = gt[0], yc = gt[1], ww = gt[2], hh = gt[3];
        float x1 = xc - ww * 0.5f, y1 = yc - hh * 0.5f;
        float x2 = xc + ww * 0.5f, y2 = yc + hh * 0.5f;
        float at = atanf((x2 - x1) / (y2 - y1));
        s_gt[tid * 5 + 0] = x1; s_gt[tid * 5 + 1] = y1;
        s_gt[tid * 5 + 2] = x2; s_gt[tid * 5 + 3] = y2;
        s_gt[tid * 5 + 4] = at;
        if (sg == 0) {
            float* gp = gtab + (size_t)(b * NGT + tid) * 5;
            gp[0] = x1; gp[1] = y1; gp[2] = x2; gp[3] = y2; gp[4] = at;
        }
    }
    // labels via ballot over the one-hot row (wave w -> 4 GT rows)
    #pragma unroll
    for (int q = 0; q < 4; ++q) {
        int m = w * 4 + q;
        const float* gt = targets + (size_t)(b * NGT + m) * ROW;
        u64 m1 = __ballot(gt[5 + lane] > 0.5f);
        float v2 = (lane < 16) ? gt[69 + lane] : 0.f;
        u64 m2 = __ballot(v2 > 0.5f);
        if (lane == 0) {
            int L = m1 ? (__ffsll(m1) - 1) : (64 + __ffsll(m2) - 1);
            s_lab[m] = L;
            if (sg == 0) larr[b * NGT + m] = L;
        }
    }
    __syncthreads();

    // S0: pred = lane, chunk w covers 10 classes
    {
        float s = 0.f;
        if (lane < nv) {
            const float* r = rows + lane * ROW;
            int c0 = w * 10;
            #pragma unroll
            for (int c = 0; c < 10; ++c) s += focal_t(r[5 + c0 + c], 0.f);
        }
        s_part[w * 64 + lane] = s;
    }
    __syncthreads();
    if (tid < 64) {
        float s = s_part[tid];
        #pragma unroll
        for (int c = 1; c < 8; ++c) s += s_part[c * 64 + tid];
        s_s0[tid] = s;
        if (tid < nv) s0arr[b * NPRED + p0 + tid] = s;
        double ng = (tid < nv) ? (double)focal_t(rows[tid * ROW + 4], 0.f) : 0.0;
        #pragma unroll
        for (int off = 32; off >= 1; off >>= 1) ng += __shfl_xor(ng, off);
        if (tid == 0) negbuf[b * NSEG + sg] = ng;   // direct write, no atomic
    }
    __syncthreads();

    // cost + top-2 segment minima: wave w -> GT rows w*4..w*4+3, lane = pred
    bool valid = lane < nv;
    const float* r = rows + lane * ROW;
    float x1 = 0.f, y1 = 0.f, x2 = 0.f, y2 = 0.f, atan_p = 0.f, S0 = 0.f;
    if (valid) {
        float xc = r[0], yc = r[1], ww = r[2], hh = r[3];
        x1 = xc - ww * 0.5f; y1 = yc - hh * 0.5f;
        x2 = xc + ww * 0.5f; y2 = yc + hh * 0.5f;
        atan_p = atanf((x2 - x1) / (y2 - y1));
        S0 = s_s0[lane];
    }
    #pragma unroll
    for (int q = 0; q < 4; ++q) {
        int m = w * 4 + q;
        const float* gp = s_gt + m * 5;
        float cost = INFINITY;
        if (valid) {
            float cc = ciou_f(x1, y1, x2, y2, gp[0], gp[1], gp[2], gp[3],
                              atan_p, gp[4]);
            float xl = r[5 + s_lab[m]];
            cost = cc + (S0 - focal_t(xl, 0.f) + focal_t(xl, 1.f)) / 80.f;
        }
        // min1 via f32 butterfly + ballot (lowest lane == lowest index)
        float v = cost;
        #pragma unroll
        for (int off = 32; off >= 1; off >>= 1) v = fminf(v, __shfl_xor(v, off));
        u64 mk1 = __ballot(cost == v);
        int l1 = __ffsll(mk1) - 1;
        int i1 = (l1 < nv) ? (p0 + l1) : NPRED;
        // min2: exclude winner lane only (matches old kx semantics)
        float c2 = (lane == l1) ? INFINITY : cost;
        float v2 = c2;
        #pragma unroll
        for (int off = 32; off >= 1; off >>= 1) v2 = fminf(v2, __shfl_xor(v2, off));
        u64 mk2 = __ballot(c2 == v2);
        int l2 = __ffsll(mk2) - 1;
        int i2 = (l2 < nv) ? (p0 + l2) : NPRED;
        if (lane == 0) {
            kt1[(size_t)(b * NGT + m) * NSEG + sg] = pack_key(v, i1);
            kt2[(size_t)(b * NGT + m) * NSEG + sg] = pack_key(v2, i2);
        }
    }
}

// ---------- K2: 4 blocks (block = batch), 512 threads --------------------
// Phase 1: 8 waves x 4 rows coalesced rowmin over kt1. Phase 2: wave 0 =
// serial assignment (reference semantics, R11 logic verbatim); wave 1 = neg
// sums (concurrent). Phase 3: finalize spread over 8 waves; per-batch
// partial doubles written to ws (unconditionally, every call).

__global__ __launch_bounds__(512) void assign_kernel(
        const float* __restrict__ outputs, const float* __restrict__ targets,
        const float* __restrict__ s0arr, const u64* __restrict__ kt1,
        const u64* __restrict__ kt2, const double* __restrict__ negbuf,
        const float* __restrict__ gtab, const int* __restrict__ larr,
        double* __restrict__ partials) {
    int b = blockIdx.x;
    int tid = threadIdx.x;
    int w = tid >> 6, lane = tid & 63;

    __shared__ u64    taken[NSEG], poison[NSEG];
    __shared__ float  s_gt[NGT * 5];
    __shared__ int    s_lab[NGT];
    __shared__ int    rmi[NGT];
    __shared__ int    s_midx[NGT];
    __shared__ float  s_siou[NGT], s_cls[NGT], s_adj[NGT];
    __shared__ double s_ns;

    if (tid < NSEG) { taken[tid] = 0ull; poison[tid] = 0ull; }
    if (tid < NGT * 5) s_gt[tid] = gtab[b * NGT * 5 + tid];
    if (tid < NGT) s_lab[tid] = larr[b * NGT + tid];

    // Phase 1: wave w -> rows w*4..w*4+3, coalesced u64 rowmin
    #pragma unroll
    for (int q = 0; q < 4; ++q) {
        int row = w * 4 + q;
        const u64* kr = kt1 + ((size_t)b * NGT + row) * NSEG;
        u64 k = kr[lane];
        { u64 v = kr[lane + 64]; if (v < k) k = v; }
        if (lane < NSEG - 128) { u64 v = kr[lane + 128]; if (v < k) k = v; }
        k = wave_min_u64(k);
        if (lane == 0) rmi[row] = (int)(unsigned)(k & 0xffffffffull);
    }
    __syncthreads();

    if (w == 0) {
        // serial assignment for batch b (reference semantics, round-0 note)
        const float* Ob = outputs + (size_t)b * NPRED * ROW;
        const float* S0b = s0arr + (size_t)b * NPRED;
        for (int i = 0; i < NGT; ++i) {
            int j1 = rmi[i];
            if ((poison[j1 >> 6] >> (j1 & 63)) & 1ull) {
                // repair: per-seg key = k1 if argmin alive, else k2 if alive,
                // else recompute (both-top2-poisoned: ~never).
                const u64* k1r = kt1 + ((size_t)b * NGT + i) * NSEG;
                const u64* k2r = kt2 + ((size_t)b * NGT + i) * NSEG;
                const float* gp = &s_gt[i * 5];
                int lab = s_lab[i];
                u64 best = ~0ull;
                for (int k0 = 0; k0 < NSEG; k0 += 64) {
                    int s = k0 + lane;
                    u64 eff = ~0ull; bool rc = false;
                    if (s < NSEG) {
                        u64 ka = k1r[s];
                        int ia = (int)(unsigned)(ka & 0xffffffffull);
                        if (!((poison[ia >> 6] >> (ia & 63)) & 1ull)) eff = ka;
                        else {
                            u64 kb = k2r[s];
                            int ib = (int)(unsigned)(kb & 0xffffffffull);
                            if (ib < NPRED && !((poison[ib >> 6] >> (ib & 63)) & 1ull)) eff = kb;
                            else rc = true;
                        }
                    }
                    u64 rm = __ballot(rc);
                    while (rm) {
                        int sgg = k0 + (__ffsll(rm) - 1);
                        rm &= rm - 1;
                        int col = (sgg << 6) + lane;
                        bool cv = (col < NPRED) && !((poison[col >> 6] >> (col & 63)) & 1ull);
                        float vv = INFINITY;
                        if (cv) {
                            const float* pr = Ob + (size_t)col * ROW;
                            float xc = pr[0], yc = pr[1], ww2 = pr[2], hh2 = pr[3];
                            float x1 = xc - ww2 * 0.5f, y1 = yc - hh2 * 0.5f;
                            float x2 = xc + ww2 * 0.5f, y2 = yc + hh2 * 0.5f;
                            float atan_p = atanf((x2 - x1) / (y2 - y1));
                            float cc = ciou_f(x1, y1, x2, y2, gp[0], gp[1], gp[2], gp[3],
                                              atan_p, gp[4]);
                            float xl = pr[5 + lab];
                            vv = cc + (S0b[col] - focal_t(xl, 0.f) + focal_t(xl, 1.f)) / 80.f;
                        }
                        u64 key = pack_key(vv, cv ? col : NPRED);
                        key = wave_min_u64(key);
                        if (s == sgg) eff = key;
                    }
                    if (eff < best) best = eff;
                }
                best = wave_min_u64(best);
                j1 = (int)(unsigned)(best & 0xffffffffull);
            }
            bool tk = (taken[j1 >> 6] >> (j1 & 63)) & 1ull;
            if (!tk) {
                if (lane == 0) { taken[j1 >> 6] |= 1ull << (j1 & 63); s_midx[i] = j1; }
            } else {
                // collision: first free col is in word 0 (<=32 taken bits ever)
                u64 tw = taken[0];
                int bit = __ffsll(~tw) - 1;
                u64 add = (lane == 0) ? (tw & ((bit == 0) ? 0ull : ((1ull << bit) - 1ull))) : 0ull;
                if ((j1 >> 6) == lane) add |= 1ull << (j1 & 63);
                if (add) poison[lane] |= add;
                int u2 = lane + 64;
                if ((j1 >> 6) == u2) poison[u2] |= 1ull << (j1 & 63);
                int u3 = lane + 128;
                if (u3 < NSEG && (j1 >> 6) == u3) poison[u3] |= 1ull << (j1 & 63);
                if (lane == 0) { taken[0] |= 1ull << bit; s_midx[i] = bit; }
            }
        }
    } else if (w == 1) {
        // concurrent: neg partial sum for batch b
        double ng = negbuf[b * NSEG + lane] + negbuf[b * NSEG + 64 + lane]
                  + ((lane < NSEG - 128) ? negbuf[b * NSEG + 128 + lane] : 0.0);
        #pragma unroll
        for (int off = 32; off >= 1; off >>= 1) ng += __shfl_xor(ng, off);
        if (lane == 0) s_ns = ng;
    }
    __syncthreads();

    // Phase 3: finalize partials for batch b
    if (tid < NGT) {               // 32 threads: ciou + obj-adjust per pair
        int m = tid, j = s_midx[m];
        const float* pr = outputs + ((size_t)b * NPRED + j) * ROW;
        float xc = pr[0], yc = pr[1], ww = pr[2], hh = pr[3];
        float x1 = xc - ww * 0.5f, y1 = yc - hh * 0.5f;
        float x2 = xc + ww * 0.5f, y2 = yc + hh * 0.5f;
        float atan_p = atanf((x2 - x1) / (y2 - y1));
        const float* gp = &s_gt[m * 5];
        s_siou[m] = ciou_f(x1, y1, x2, y2, gp[0], gp[1], gp[2], gp[3], atan_p, gp[4]);
        float conf = pr[4];
        s_adj[m] = focal_t(conf, 1.f) - focal_t(conf, 0.f);
    }
    // cls: wave w -> pairs w*4..w*4+3, lane-parallel over classes
    #pragma unroll
    for (int q = 0; q < 4; ++q) {
        int m = w * 4 + q;
        int j = s_midx[m];
        const float* pr = outputs + ((size_t)b * NPRED + j) * ROW;
        const float* gt = targets + ((size_t)b * NGT + m) * ROW;
        float s = focal_t(pr[5 + lane], gt[5 + lane]);
        if (lane < 16) s += focal_t(pr[69 + lane], gt[69 + lane]);
        #pragma unroll
        for (int off = 32; off >= 1; off >>= 1) s += __shfl_xor(s, off);
        if (lane == 0) s_cls[m] = s / 80.f;
    }
    __syncthreads();

    // wave 0: fixed-order per-batch reduce, write partials
    if (w == 0) {
        double ss = (lane < NGT) ? (double)s_siou[lane] : 0.0;
        double cs = (lane < NGT) ? (double)s_cls[lane] : 0.0;
        double as = (lane < NGT) ? (double)s_adj[lane] : 0.0;
        #pragma unroll
        for (int off = 32; off >= 1; off >>= 1) {
            ss += __shfl_xor(ss, off);
            cs += __shfl_xor(cs, off);
            as += __shfl_xor(as, off);
        }
        if (lane == 0) {
            partials[b * 4 + 0] = ss;
            partials[b * 4 + 1] = cs;
            partials[b * 4 + 2] = as;
            partials[b * 4 + 3] = s_ns;
        }
    }
}

// ---------- K3: tiny deterministic combine ----------

__global__ __launch_bounds__(64) void combine_kernel(
        const double* __restrict__ partials, float* __restrict__ out) {
    if (threadIdx.x == 0) {
        double S = 0.0, C = 0.0, A = 0.0, N = 0.0;
        #pragma unroll
        for (int b = 0; b < NB; ++b) {
            S += partials[b * 4 + 0];
            C += partials[b * 4 + 1];
            A += partials[b * 4 + 2];
            N += partials[b * 4 + 3];
        }
        float siou = (float)(S / 128.0);
        float cls  = (float)(C / 128.0);
        float obj  = (float)((N + A) / (double)(NB * NPRED));
        out[0] = 2.0f * siou + 2.0f * obj + 2.0f * cls;
        out[1] = siou;
        out[2] = obj;
        out[3] = cls;
    }
}

// ---------- launch ----------

extern "C" void kernel_launch(void* const* d_in, const int* in_sizes, int n_in,
                              void* d_out, int out_size, void* d_ws, size_t ws_size,
                              hipStream_t stream) {
    const float* outputs = (const float*)d_in[0];
    const float* targets = (const float*)d_in[1];
    float* out = (float*)d_out;

    char* ws = (char*)d_ws;
    double* negbuf = (double*)ws;                     // 4*132*8 = 4224 B
    float* gtab = (float*)(ws + 4352);                // 2560 B
    int* larr = (int*)(ws + 7040);                    // 512 B
    float* s0arr = (float*)(ws + 7552);               // 134400 B
    u64* kt1 = (u64*)(ws + 141952);                   // 135168 B
    u64* kt2 = (u64*)(ws + 277120);                   // 135168 B
    double* partials = (double*)(ws + 412288);        // 128 B

    dim3 g1(NSEG, NB);                                // 132 x 4 segment blocks
    fused_kernel<<<g1, 512, 0, stream>>>(outputs, targets, s0arr, kt1, kt2,
                                         negbuf, gtab, larr);

    assign_kernel<<<NB, 512, 0, stream>>>(outputs, targets, s0arr, kt1, kt2,
                                          negbuf, gtab, larr, partials);

    combine_kernel<<<1, 64, 0, stream>>>(partials, out);
}